// Round 4
// baseline (358.524 us; speedup 1.0000x reference)
//
#include <hip/hip_runtime.h>
#include <cstddef>

// VOneBlock R8: gabor de-LDS'd.
// gabor: x window per (og,ky) is wave-uniform (b, oh, og, ky uniform; only channel c
// is per-lane) -> load x via uniform/scalar loads straight from global (L1/L2-cached,
// ~2MB), keep weights in VGPRs; v_fmac uses the single allowed SGPR operand.
// Removes xbuf staging, both barriers, and all LDS issue/wait from the inner loop.
// Border handling is uniform scalar branches. FMA order identical to R7 -> bit-identical.
// dn: unchanged from R7 (reg-staged async split, 3-buffer rotation, XOR swizzle).
// ws: [0, 134217728) y2 fp16 [b][h][w][hi 256ci | lo 256ci]; then gf fp16 fragment-ordered.

#define NSC 128
#define GSCALE 64.0f

typedef float f4v __attribute__((ext_vector_type(4)));
typedef _Float16 h8v __attribute__((ext_vector_type(8)));

__device__ __forceinline__ short f2h(float f) {
    return __builtin_bit_cast(short, (_Float16)f);
}
__device__ __forceinline__ float h2f(short s) {
    return (float)__builtin_bit_cast(_Float16, s);
}

__global__ __launch_bounds__(256) void prep_g(const float* __restrict__ g,
                                              short* __restrict__ gf) {
    int t = blockIdx.x * 256 + threadIdx.x;      // 589824 = 9*256*256
    int co = t & 255, ci = (t >> 8) & 255, kxy = t >> 16;
    float v = g[((size_t)co * 256 + ci) * 9 + kxy] * (1.0f / GSCALE);
    v = fminf(v, 65504.f);                       // saturate instead of inf
    int wv = co >> 6, m = (co >> 4) & 3, i = co & 15;
    int cc = ci >> 5, q = (ci >> 3) & 3, j = ci & 7;
    int l = q * 16 + i;
    size_t base = ((((size_t)(kxy * 4 + wv) * 4 + m) * 8 + cc)) * 512 + (size_t)l * 8 + j;
    gf[base] = f2h(v);
}

__global__ __launch_bounds__(256) void gabor(const float* __restrict__ x,
                                             const float* __restrict__ wq0,
                                             const float* __restrict__ wq1,
                                             short* __restrict__ y2) {
    int oh = blockIdx.x, b = blockIdx.y, c = threadIdx.x;
    int ihb = oh * 2 - 2;
    const float* xb = x + (size_t)b * 128 * 128;
    short* yb = y2 + ((size_t)(b * 64 + oh) * 64) * 512 + c;

    if (c < NSC) {
        float w0[25];
#pragma unroll
        for (int i = 0; i < 25; ++i) w0[i] = wq0[c * 25 + i];
        for (int og = 0; og < 16; ++og) {
            int cb = og * 8 - 2;
            float q0[4] = {0.f, 0.f, 0.f, 0.f};
            for (int ky = 0; ky < 5; ++ky) {
                int ih = ihb + ky;
                if ((unsigned)ih >= 128u) continue;          // uniform branch
                const float* xr = xb + (size_t)ih * 128;
                float sx[12];
                if (og != 0 && og != 15) {
#pragma unroll
                    for (int k = 0; k < 12; ++k) sx[k] = xr[cb + k];
                } else {
#pragma unroll
                    for (int k = 0; k < 12; ++k) {
                        int col = cb + k;
                        sx[k] = ((unsigned)col < 128u) ? xr[col] : 0.f;
                    }
                }
#pragma unroll
                for (int j = 0; j < 4; ++j)
#pragma unroll
                    for (int kx = 0; kx < 5; ++kx)
                        q0[j] = fmaf(w0[ky * 5 + kx], sx[2 * j + kx], q0[j]);
            }
#pragma unroll
            for (int j = 0; j < 4; ++j) {
                float v = 25.f * fmaxf(q0[j], 0.f);
                short hi = f2h(v);
                short lo = f2h(v - h2f(hi));
                int ow = og * 4 + j;
                yb[(size_t)ow * 512] = hi;
                yb[(size_t)ow * 512 + 256] = lo;
            }
        }
    } else {
        float w0[25], w1[25];
#pragma unroll
        for (int i = 0; i < 25; ++i) w0[i] = wq0[c * 25 + i];
#pragma unroll
        for (int i = 0; i < 25; ++i) w1[i] = wq1[c * 25 + i];
        for (int og = 0; og < 16; ++og) {
            int cb = og * 8 - 2;
            float q0[4] = {0.f, 0.f, 0.f, 0.f}, q1[4] = {0.f, 0.f, 0.f, 0.f};
            for (int ky = 0; ky < 5; ++ky) {
                int ih = ihb + ky;
                if ((unsigned)ih >= 128u) continue;          // uniform branch
                const float* xr = xb + (size_t)ih * 128;
                float sx[12];
                if (og != 0 && og != 15) {
#pragma unroll
                    for (int k = 0; k < 12; ++k) sx[k] = xr[cb + k];
                } else {
#pragma unroll
                    for (int k = 0; k < 12; ++k) {
                        int col = cb + k;
                        sx[k] = ((unsigned)col < 128u) ? xr[col] : 0.f;
                    }
                }
#pragma unroll
                for (int j = 0; j < 4; ++j)
#pragma unroll
                    for (int kx = 0; kx < 5; ++kx) {
                        q0[j] = fmaf(w0[ky * 5 + kx], sx[2 * j + kx], q0[j]);
                        q1[j] = fmaf(w1[ky * 5 + kx], sx[2 * j + kx], q1[j]);
                    }
            }
#pragma unroll
            for (int j = 0; j < 4; ++j) {
                float v = 25.f * sqrtf(fmaf(q0[j], q0[j], q1[j] * q1[j])) * 0.70710678118654752f;
                short hi = f2h(v);
                short lo = f2h(v - h2f(hi));
                int ow = og * 4 + j;
                yb[(size_t)ow * 512] = hi;
                yb[(size_t)ow * 512 + 256] = lo;
            }
        }
    }
}

// Load one input-row-half into 4 float4 regs, source address pre-swizzled so the
// linear LDS layout reads back correctly with g ^= (w66&7).
__device__ __forceinline__ void stage_load(const short* __restrict__ y2, float4* sr,
                                           int b, int r, int half, int tid) {
    if ((unsigned)r < 64u) {
        const short* rowbase = y2 + (size_t)((b * 64 + r) * 64) * 512;
#pragma unroll
        for (int p4 = 0; p4 < 4; ++p4) {
            int i = p4 * 256 + tid;
            int w66 = (i >> 4) + 1, g = i & 15;
            int sg = ((w66 - 1) << 6) + half * 16 + (g ^ (w66 & 7));
            sr[p4] = *(const float4*)(rowbase + (size_t)sg * 8);
        }
    } else {
#pragma unroll
        for (int p4 = 0; p4 < 4; ++p4) sr[p4] = (float4){0.f, 0.f, 0.f, 0.f};
    }
}

__device__ __forceinline__ void stage_write(short* __restrict__ buf, const float4* sr,
                                            int tid) {
#pragma unroll
    for (int p4 = 0; p4 < 4; ++p4) {
        int i = p4 * 256 + tid;
        *(float4*)(buf + (size_t)(16 + i) * 8) = sr[p4];
    }
}

// block = (ht, b): 256 co x 64 w x 2 h-rows. 4 waves, each 64co x 64w x 2h.
__global__ __launch_bounds__(256, 2) void dn(const short* __restrict__ y2,
                                             const short* __restrict__ gf,
                                             float* __restrict__ out) {
    __shared__ short bbuf[3][66 * 16 * 8];   // 3-rotation row buffers; w66 0/65 = zero halo
    int h = blockIdx.x * 2, b = blockIdx.y;
    int tid = threadIdx.x;
    int wv = tid >> 6, l = tid & 63;
    int li = l & 15, lq = l >> 4;

    // zero halo rows (w66 = 0, 65) in all 3 buffers, once
    if (tid < 96) {
        int bi = tid >> 5, t2 = tid & 31;
        int row = (t2 >> 4) ? 65 : 0, g = t2 & 15;
        *(float4*)&bbuf[bi][(row * 16 + g) * 8] = (float4){0.f, 0.f, 0.f, 0.f};
    }

    f4v acc[2][4][4];
#pragma unroll
    for (int hs = 0; hs < 2; ++hs)
#pragma unroll
        for (int m = 0; m < 4; ++m)
#pragma unroll
            for (int n = 0; n < 4; ++n)
                acc[hs][m][n] = (f4v){0.f, 0.f, 0.f, 0.f};

    const h8v* GA = (const h8v*)gf;

    for (int half = 0; half < 2; ++half) {
        float4 sr[4];
        // prologue: stage rows h-1, h (latency exposed here only)
        stage_load(y2, sr, b, h - 1, half, tid);
        stage_write(bbuf[(h + 2) % 3], sr, tid);
        stage_load(y2, sr, b, h, half, tid);
        stage_write(bbuf[h % 3], sr, tid);
        __syncthreads();

        for (int ky = 0; ky < 3; ++ky) {
            // issue next row's loads FIRST; the MFMA phase hides their latency
            if (ky < 2)
                stage_load(y2, sr, b, h + ky + 1, half, tid);

            const h8v* B0 = (const h8v*)bbuf[(h + ky + 2) % 3];  // row h-1+ky
            const h8v* B1 = (const h8v*)bbuf[(h + ky) % 3];      // row h+ky

            for (int kx = 0; kx < 3; ++kx) {
                int kxy = ky * 3 + kx;
#pragma unroll
                for (int cc = 0; cc < 4; ++cc) {
                    int ccg = half * 4 + cc;
                    h8v Ah[4];
#pragma unroll
                    for (int m = 0; m < 4; ++m) {
                        size_t ab = ((((size_t)(kxy * 4 + wv) * 4 + m) * 8 + ccg)) * 64 + l;
                        Ah[m] = GA[ab];
                    }
#pragma unroll
                    for (int hs = 0; hs < 2; ++hs) {
                        const h8v* BH = hs ? B1 : B0;
                        h8v Bh[4];
#pragma unroll
                        for (int nt = 0; nt < 4; ++nt) {
                            int w66 = nt * 16 + li + kx;
                            int g = (cc * 4 + lq) ^ (w66 & 7);
                            Bh[nt] = BH[w66 * 16 + g];
                        }
#pragma unroll
                        for (int m = 0; m < 4; ++m)
#pragma unroll
                            for (int nt = 0; nt < 4; ++nt)
                                acc[hs][m][nt] = __builtin_amdgcn_mfma_f32_16x16x32_f16(Ah[m], Bh[nt], acc[hs][m][nt], 0, 0, 0);
                    }
                }
            }

            // write the prefetched row into the buffer nobody reads this phase
            // (distinct mod-3 from both read buffers -> no intra-phase race)
            if (ky < 2)
                stage_write(bbuf[(h + ky + 1) % 3], sr, tid);
            __syncthreads();
        }
    }

    // epilogue: out = y / (GSCALE * under_scaled), write NCHW for rows h and h+1
#pragma unroll
    for (int hs = 0; hs < 2; ++hs) {
        const short* nrow = y2 + (size_t)((b * 64 + h + hs) * 64) * 512;
#pragma unroll
        for (int m = 0; m < 4; ++m) {
            int co = wv * 64 + m * 16 + lq * 4;
#pragma unroll
            for (int nt = 0; nt < 4; ++nt) {
                int w = nt * 16 + li;
                const short* np = nrow + (size_t)w * 512 + co;
                ushort4 nh = *(const ushort4*)np;
                ushort4 nl = *(const ushort4*)(np + 256);
                float n0 = h2f((short)nh.x) + h2f((short)nl.x);
                float n1 = h2f((short)nh.y) + h2f((short)nl.y);
                float n2 = h2f((short)nh.z) + h2f((short)nl.z);
                float n3 = h2f((short)nh.w) + h2f((short)nl.w);
                size_t ob = ((size_t)(b * 256 + co) * 64 + (h + hs)) * 64 + w;
                out[ob]            = n0 / (GSCALE * acc[hs][m][nt][0]);
                out[ob + 4096]     = n1 / (GSCALE * acc[hs][m][nt][1]);
                out[ob + 2 * 4096] = n2 / (GSCALE * acc[hs][m][nt][2]);
                out[ob + 3 * 4096] = n3 / (GSCALE * acc[hs][m][nt][3]);
            }
        }
    }
}

extern "C" void kernel_launch(void* const* d_in, const int* in_sizes, int n_in,
                              void* d_out, int out_size, void* d_ws, size_t ws_size,
                              hipStream_t stream) {
    const float* x   = (const float*)d_in[0];
    const float* wq0 = (const float*)d_in[1];
    const float* wq1 = (const float*)d_in[2];
    const float* g   = (const float*)d_in[3];
    float* out = (float*)d_out;
    short* y2 = (short*)d_ws;
    short* gf = y2 + 67108864;

    prep_g<<<2304, 256, 0, stream>>>(g, gf);
    gabor<<<dim3(64, 32), 256, 0, stream>>>(x, wq0, wq1, y2);
    dn<<<dim3(32, 32), 256, 0, stream>>>(y2, gf, out);
}

// Round 5
// 330.552 us; speedup vs baseline: 1.0846x; 1.0846x over previous
//
#include <hip/hip_runtime.h>
#include <cstddef>

// VOneBlock R9: gabor reverted to R7 LDS-xbuf structure (R8 de-LDS regressed);
// weight loads fixed. wq0/wq1 are [256][25] -> per-lane stride-100B scatter
// (~50 cachelines per load inst, TA-serialized). prep_g now also transposes them
// into wt0/wt1 [25][256] f32 in ws; gabor loads wt[i*256+c] fully coalesced.
// FMA order unchanged -> bit-identical to R7. dn unchanged from R7.
// ws: y2 fp16 [b][h][w][hi|lo 256ci] (128MB); gf fp16 fragment-ordered (1.18MB);
//     wt0, wt1 f32 [25][256] (25.6KB each).

#define NSC 128
#define GSCALE 64.0f

typedef float f4v __attribute__((ext_vector_type(4)));
typedef _Float16 h8v __attribute__((ext_vector_type(8)));

__device__ __forceinline__ short f2h(float f) {
    return __builtin_bit_cast(short, (_Float16)f);
}
__device__ __forceinline__ float h2f(short s) {
    return (float)__builtin_bit_cast(_Float16, s);
}

__global__ __launch_bounds__(256) void prep_g(const float* __restrict__ g,
                                              const float* __restrict__ wq0,
                                              const float* __restrict__ wq1,
                                              short* __restrict__ gf,
                                              float* __restrict__ wt0,
                                              float* __restrict__ wt1) {
    int t = blockIdx.x * 256 + threadIdx.x;      // 589824 = 9*256*256
    // weight transpose: [256][25] -> [25][256] (coalesced reads, 12800 scattered writes)
    if (t < 6400) {
        wt0[(t % 25) * 256 + t / 25] = wq0[t];
        wt1[(t % 25) * 256 + t / 25] = wq1[t];
    }
    int co = t & 255, ci = (t >> 8) & 255, kxy = t >> 16;
    float v = g[((size_t)co * 256 + ci) * 9 + kxy] * (1.0f / GSCALE);
    v = fminf(v, 65504.f);                       // saturate instead of inf
    int wv = co >> 6, m = (co >> 4) & 3, i = co & 15;
    int cc = ci >> 5, q = (ci >> 3) & 3, j = ci & 7;
    int l = q * 16 + i;
    size_t base = ((((size_t)(kxy * 4 + wv) * 4 + m) * 8 + cc)) * 512 + (size_t)l * 8 + j;
    gf[base] = f2h(v);
}

__global__ __launch_bounds__(256) void gabor(const float* __restrict__ x,
                                             const float* __restrict__ wt0,
                                             const float* __restrict__ wt1,
                                             short* __restrict__ y2) {
    __shared__ float xbuf[5][132];
    int oh = blockIdx.x, b = blockIdx.y, c = threadIdx.x;
    for (int i = c; i < 5 * 132; i += 256) (&xbuf[0][0])[i] = 0.f;
    __syncthreads();
    int ihb = oh * 2 - 2;
    for (int i = c; i < 5 * 128; i += 256) {
        int r = i >> 7, col = i & 127;
        int ih = ihb + r;
        if ((unsigned)ih < 128u)
            xbuf[r][col + 2] = x[((size_t)b * 128 + ih) * 128 + col];
    }
    short* yb = y2 + ((size_t)(b * 64 + oh) * 64) * 512 + c;

    if (c < NSC) {
        float w0[25];
#pragma unroll
        for (int i = 0; i < 25; ++i) w0[i] = wt0[i * 256 + c];   // coalesced
        __syncthreads();
        for (int og = 0; og < 16; ++og) {
            int cb = og * 8;
            float q0[4] = {0.f, 0.f, 0.f, 0.f};
#pragma unroll
            for (int ky = 0; ky < 5; ++ky) {
                float xr[12];
                *(float4*)&xr[0] = *(const float4*)&xbuf[ky][cb];
                *(float4*)&xr[4] = *(const float4*)&xbuf[ky][cb + 4];
                *(float4*)&xr[8] = *(const float4*)&xbuf[ky][cb + 8];
#pragma unroll
                for (int j = 0; j < 4; ++j)
#pragma unroll
                    for (int kx = 0; kx < 5; ++kx)
                        q0[j] = fmaf(w0[ky * 5 + kx], xr[2 * j + kx], q0[j]);
            }
#pragma unroll
            for (int j = 0; j < 4; ++j) {
                float v = 25.f * fmaxf(q0[j], 0.f);
                short hi = f2h(v);
                short lo = f2h(v - h2f(hi));
                int ow = og * 4 + j;
                yb[(size_t)ow * 512] = hi;
                yb[(size_t)ow * 512 + 256] = lo;
            }
        }
    } else {
        float w0[25], w1[25];
#pragma unroll
        for (int i = 0; i < 25; ++i) w0[i] = wt0[i * 256 + c];   // coalesced
#pragma unroll
        for (int i = 0; i < 25; ++i) w1[i] = wt1[i * 256 + c];   // coalesced
        __syncthreads();
        for (int og = 0; og < 16; ++og) {
            int cb = og * 8;
            float q0[4] = {0.f, 0.f, 0.f, 0.f}, q1[4] = {0.f, 0.f, 0.f, 0.f};
#pragma unroll
            for (int ky = 0; ky < 5; ++ky) {
                float xr[12];
                *(float4*)&xr[0] = *(const float4*)&xbuf[ky][cb];
                *(float4*)&xr[4] = *(const float4*)&xbuf[ky][cb + 4];
                *(float4*)&xr[8] = *(const float4*)&xbuf[ky][cb + 8];
#pragma unroll
                for (int j = 0; j < 4; ++j)
#pragma unroll
                    for (int kx = 0; kx < 5; ++kx) {
                        q0[j] = fmaf(w0[ky * 5 + kx], xr[2 * j + kx], q0[j]);
                        q1[j] = fmaf(w1[ky * 5 + kx], xr[2 * j + kx], q1[j]);
                    }
            }
#pragma unroll
            for (int j = 0; j < 4; ++j) {
                float v = 25.f * sqrtf(fmaf(q0[j], q0[j], q1[j] * q1[j])) * 0.70710678118654752f;
                short hi = f2h(v);
                short lo = f2h(v - h2f(hi));
                int ow = og * 4 + j;
                yb[(size_t)ow * 512] = hi;
                yb[(size_t)ow * 512 + 256] = lo;
            }
        }
    }
}

// Load one input-row-half into 4 float4 regs, source address pre-swizzled so the
// linear LDS layout reads back correctly with g ^= (w66&7).
__device__ __forceinline__ void stage_load(const short* __restrict__ y2, float4* sr,
                                           int b, int r, int half, int tid) {
    if ((unsigned)r < 64u) {
        const short* rowbase = y2 + (size_t)((b * 64 + r) * 64) * 512;
#pragma unroll
        for (int p4 = 0; p4 < 4; ++p4) {
            int i = p4 * 256 + tid;
            int w66 = (i >> 4) + 1, g = i & 15;
            int sg = ((w66 - 1) << 6) + half * 16 + (g ^ (w66 & 7));
            sr[p4] = *(const float4*)(rowbase + (size_t)sg * 8);
        }
    } else {
#pragma unroll
        for (int p4 = 0; p4 < 4; ++p4) sr[p4] = (float4){0.f, 0.f, 0.f, 0.f};
    }
}

__device__ __forceinline__ void stage_write(short* __restrict__ buf, const float4* sr,
                                            int tid) {
#pragma unroll
    for (int p4 = 0; p4 < 4; ++p4) {
        int i = p4 * 256 + tid;
        *(float4*)(buf + (size_t)(16 + i) * 8) = sr[p4];
    }
}

// block = (ht, b): 256 co x 64 w x 2 h-rows. 4 waves, each 64co x 64w x 2h.
__global__ __launch_bounds__(256, 2) void dn(const short* __restrict__ y2,
                                             const short* __restrict__ gf,
                                             float* __restrict__ out) {
    __shared__ short bbuf[3][66 * 16 * 8];   // 3-rotation row buffers; w66 0/65 = zero halo
    int h = blockIdx.x * 2, b = blockIdx.y;
    int tid = threadIdx.x;
    int wv = tid >> 6, l = tid & 63;
    int li = l & 15, lq = l >> 4;

    // zero halo rows (w66 = 0, 65) in all 3 buffers, once
    if (tid < 96) {
        int bi = tid >> 5, t2 = tid & 31;
        int row = (t2 >> 4) ? 65 : 0, g = t2 & 15;
        *(float4*)&bbuf[bi][(row * 16 + g) * 8] = (float4){0.f, 0.f, 0.f, 0.f};
    }

    f4v acc[2][4][4];
#pragma unroll
    for (int hs = 0; hs < 2; ++hs)
#pragma unroll
        for (int m = 0; m < 4; ++m)
#pragma unroll
            for (int n = 0; n < 4; ++n)
                acc[hs][m][n] = (f4v){0.f, 0.f, 0.f, 0.f};

    const h8v* GA = (const h8v*)gf;

    for (int half = 0; half < 2; ++half) {
        float4 sr[4];
        // prologue: stage rows h-1, h (latency exposed here only)
        stage_load(y2, sr, b, h - 1, half, tid);
        stage_write(bbuf[(h + 2) % 3], sr, tid);
        stage_load(y2, sr, b, h, half, tid);
        stage_write(bbuf[h % 3], sr, tid);
        __syncthreads();

        for (int ky = 0; ky < 3; ++ky) {
            // issue next row's loads FIRST; the MFMA phase hides their latency
            if (ky < 2)
                stage_load(y2, sr, b, h + ky + 1, half, tid);

            const h8v* B0 = (const h8v*)bbuf[(h + ky + 2) % 3];  // row h-1+ky
            const h8v* B1 = (const h8v*)bbuf[(h + ky) % 3];      // row h+ky

            for (int kx = 0; kx < 3; ++kx) {
                int kxy = ky * 3 + kx;
#pragma unroll
                for (int cc = 0; cc < 4; ++cc) {
                    int ccg = half * 4 + cc;
                    h8v Ah[4];
#pragma unroll
                    for (int m = 0; m < 4; ++m) {
                        size_t ab = ((((size_t)(kxy * 4 + wv) * 4 + m) * 8 + ccg)) * 64 + l;
                        Ah[m] = GA[ab];
                    }
#pragma unroll
                    for (int hs = 0; hs < 2; ++hs) {
                        const h8v* BH = hs ? B1 : B0;
                        h8v Bh[4];
#pragma unroll
                        for (int nt = 0; nt < 4; ++nt) {
                            int w66 = nt * 16 + li + kx;
                            int g = (cc * 4 + lq) ^ (w66 & 7);
                            Bh[nt] = BH[w66 * 16 + g];
                        }
#pragma unroll
                        for (int m = 0; m < 4; ++m)
#pragma unroll
                            for (int nt = 0; nt < 4; ++nt)
                                acc[hs][m][nt] = __builtin_amdgcn_mfma_f32_16x16x32_f16(Ah[m], Bh[nt], acc[hs][m][nt], 0, 0, 0);
                    }
                }
            }

            // write the prefetched row into the buffer nobody reads this phase
            // (distinct mod-3 from both read buffers -> no intra-phase race)
            if (ky < 2)
                stage_write(bbuf[(h + ky + 1) % 3], sr, tid);
            __syncthreads();
        }
    }

    // epilogue: out = y / (GSCALE * under_scaled), write NCHW for rows h and h+1
#pragma unroll
    for (int hs = 0; hs < 2; ++hs) {
        const short* nrow = y2 + (size_t)((b * 64 + h + hs) * 64) * 512;
#pragma unroll
        for (int m = 0; m < 4; ++m) {
            int co = wv * 64 + m * 16 + lq * 4;
#pragma unroll
            for (int nt = 0; nt < 4; ++nt) {
                int w = nt * 16 + li;
                const short* np = nrow + (size_t)w * 512 + co;
                ushort4 nh = *(const ushort4*)np;
                ushort4 nl = *(const ushort4*)(np + 256);
                float n0 = h2f((short)nh.x) + h2f((short)nl.x);
                float n1 = h2f((short)nh.y) + h2f((short)nl.y);
                float n2 = h2f((short)nh.z) + h2f((short)nl.z);
                float n3 = h2f((short)nh.w) + h2f((short)nl.w);
                size_t ob = ((size_t)(b * 256 + co) * 64 + (h + hs)) * 64 + w;
                out[ob]            = n0 / (GSCALE * acc[hs][m][nt][0]);
                out[ob + 4096]     = n1 / (GSCALE * acc[hs][m][nt][1]);
                out[ob + 2 * 4096] = n2 / (GSCALE * acc[hs][m][nt][2]);
                out[ob + 3 * 4096] = n3 / (GSCALE * acc[hs][m][nt][3]);
            }
        }
    }
}

extern "C" void kernel_launch(void* const* d_in, const int* in_sizes, int n_in,
                              void* d_out, int out_size, void* d_ws, size_t ws_size,
                              hipStream_t stream) {
    const float* x   = (const float*)d_in[0];
    const float* wq0 = (const float*)d_in[1];
    const float* wq1 = (const float*)d_in[2];
    const float* g   = (const float*)d_in[3];
    float* out = (float*)d_out;
    short* y2 = (short*)d_ws;
    short* gf = y2 + 67108864;                       // 1.18MB fp16
    float* wt0 = (float*)(gf + 589824);              // [25][256] f32
    float* wt1 = wt0 + 6400;

    prep_g<<<2304, 256, 0, stream>>>(g, wq0, wq1, gf, wt0, wt1);
    gabor<<<dim3(64, 32), 256, 0, stream>>>(x, wt0, wt1, y2);
    dn<<<dim3(32, 32), 256, 0, stream>>>(y2, gf, out);
}

// Round 6
// 305.614 us; speedup vs baseline: 1.1731x; 1.0816x over previous
//
#include <hip/hip_runtime.h>
#include <cstddef>

// VOneBlock R10: drop the lo plane. Since R5, dn's MFMA consumes only the hi fp16
// plane; lo existed solely to refine the epilogue numerator (<=4.9e-4 relative).
// That cost 64MB gabor stores + 64MB dn epilogue reads per iteration. Dropped:
// y2 is now a single fp16 plane [b][h][w][256ci] (64MB). Numerator = fp16(y),
// predicted absmax ~3-6e-4 (out ~ O(1)).
// gabor: R7 LDS-xbuf structure, coalesced transposed weights, 1 store/output.
// dn: unchanged MFMA/rotation/swizzle; stage granules (w-1)*32 + half*16 + g^swz.
// ws: y2 fp16 64MB; gf fp16 fragment-ordered 1.18MB; wt0/wt1 f32 [25][256].

#define NSC 128
#define GSCALE 64.0f

typedef float f4v __attribute__((ext_vector_type(4)));
typedef _Float16 h8v __attribute__((ext_vector_type(8)));

__device__ __forceinline__ short f2h(float f) {
    return __builtin_bit_cast(short, (_Float16)f);
}
__device__ __forceinline__ float h2f(short s) {
    return (float)__builtin_bit_cast(_Float16, s);
}

__global__ __launch_bounds__(256) void prep_g(const float* __restrict__ g,
                                              const float* __restrict__ wq0,
                                              const float* __restrict__ wq1,
                                              short* __restrict__ gf,
                                              float* __restrict__ wt0,
                                              float* __restrict__ wt1) {
    int t = blockIdx.x * 256 + threadIdx.x;      // 589824 = 9*256*256
    // weight transpose: [256][25] -> [25][256]
    if (t < 6400) {
        wt0[(t % 25) * 256 + t / 25] = wq0[t];
        wt1[(t % 25) * 256 + t / 25] = wq1[t];
    }
    int co = t & 255, ci = (t >> 8) & 255, kxy = t >> 16;
    float v = g[((size_t)co * 256 + ci) * 9 + kxy] * (1.0f / GSCALE);
    v = fminf(v, 65504.f);                       // saturate instead of inf
    int wv = co >> 6, m = (co >> 4) & 3, i = co & 15;
    int cc = ci >> 5, q = (ci >> 3) & 3, j = ci & 7;
    int l = q * 16 + i;
    size_t base = ((((size_t)(kxy * 4 + wv) * 4 + m) * 8 + cc)) * 512 + (size_t)l * 8 + j;
    gf[base] = f2h(v);
}

__global__ __launch_bounds__(256) void gabor(const float* __restrict__ x,
                                             const float* __restrict__ wt0,
                                             const float* __restrict__ wt1,
                                             short* __restrict__ y2) {
    __shared__ float xbuf[5][132];
    int oh = blockIdx.x, b = blockIdx.y, c = threadIdx.x;
    for (int i = c; i < 5 * 132; i += 256) (&xbuf[0][0])[i] = 0.f;
    __syncthreads();
    int ihb = oh * 2 - 2;
    for (int i = c; i < 5 * 128; i += 256) {
        int r = i >> 7, col = i & 127;
        int ih = ihb + r;
        if ((unsigned)ih < 128u)
            xbuf[r][col + 2] = x[((size_t)b * 128 + ih) * 128 + col];
    }
    short* yb = y2 + ((size_t)(b * 64 + oh) * 64) * 256 + c;

    if (c < NSC) {
        float w0[25];
#pragma unroll
        for (int i = 0; i < 25; ++i) w0[i] = wt0[i * 256 + c];   // coalesced
        __syncthreads();
        for (int og = 0; og < 16; ++og) {
            int cb = og * 8;
            float q0[4] = {0.f, 0.f, 0.f, 0.f};
#pragma unroll
            for (int ky = 0; ky < 5; ++ky) {
                float xr[12];
                *(float4*)&xr[0] = *(const float4*)&xbuf[ky][cb];
                *(float4*)&xr[4] = *(const float4*)&xbuf[ky][cb + 4];
                *(float4*)&xr[8] = *(const float4*)&xbuf[ky][cb + 8];
#pragma unroll
                for (int j = 0; j < 4; ++j)
#pragma unroll
                    for (int kx = 0; kx < 5; ++kx)
                        q0[j] = fmaf(w0[ky * 5 + kx], xr[2 * j + kx], q0[j]);
            }
#pragma unroll
            for (int j = 0; j < 4; ++j) {
                float v = 25.f * fmaxf(q0[j], 0.f);
                yb[(size_t)(og * 4 + j) * 256] = f2h(v);
            }
        }
    } else {
        float w0[25], w1[25];
#pragma unroll
        for (int i = 0; i < 25; ++i) w0[i] = wt0[i * 256 + c];   // coalesced
#pragma unroll
        for (int i = 0; i < 25; ++i) w1[i] = wt1[i * 256 + c];   // coalesced
        __syncthreads();
        for (int og = 0; og < 16; ++og) {
            int cb = og * 8;
            float q0[4] = {0.f, 0.f, 0.f, 0.f}, q1[4] = {0.f, 0.f, 0.f, 0.f};
#pragma unroll
            for (int ky = 0; ky < 5; ++ky) {
                float xr[12];
                *(float4*)&xr[0] = *(const float4*)&xbuf[ky][cb];
                *(float4*)&xr[4] = *(const float4*)&xbuf[ky][cb + 4];
                *(float4*)&xr[8] = *(const float4*)&xbuf[ky][cb + 8];
#pragma unroll
                for (int j = 0; j < 4; ++j)
#pragma unroll
                    for (int kx = 0; kx < 5; ++kx) {
                        q0[j] = fmaf(w0[ky * 5 + kx], xr[2 * j + kx], q0[j]);
                        q1[j] = fmaf(w1[ky * 5 + kx], xr[2 * j + kx], q1[j]);
                    }
            }
#pragma unroll
            for (int j = 0; j < 4; ++j) {
                float v = 25.f * sqrtf(fmaf(q0[j], q0[j], q1[j] * q1[j])) * 0.70710678118654752f;
                yb[(size_t)(og * 4 + j) * 256] = f2h(v);
            }
        }
    }
}

// Load one input-row-half into 4 float4 regs, source address pre-swizzled so the
// linear LDS layout reads back correctly with g ^= (w66&7).
__device__ __forceinline__ void stage_load(const short* __restrict__ y2, float4* sr,
                                           int b, int r, int half, int tid) {
    if ((unsigned)r < 64u) {
        const short* rowbase = y2 + (size_t)((b * 64 + r) * 64) * 256;
#pragma unroll
        for (int p4 = 0; p4 < 4; ++p4) {
            int i = p4 * 256 + tid;
            int w66 = (i >> 4) + 1, g = i & 15;
            int sg = ((w66 - 1) << 5) + half * 16 + (g ^ (w66 & 7));
            sr[p4] = *(const float4*)(rowbase + (size_t)sg * 8);
        }
    } else {
#pragma unroll
        for (int p4 = 0; p4 < 4; ++p4) sr[p4] = (float4){0.f, 0.f, 0.f, 0.f};
    }
}

__device__ __forceinline__ void stage_write(short* __restrict__ buf, const float4* sr,
                                            int tid) {
#pragma unroll
    for (int p4 = 0; p4 < 4; ++p4) {
        int i = p4 * 256 + tid;
        *(float4*)(buf + (size_t)(16 + i) * 8) = sr[p4];
    }
}

// block = (ht, b): 256 co x 64 w x 2 h-rows. 4 waves, each 64co x 64w x 2h.
__global__ __launch_bounds__(256, 2) void dn(const short* __restrict__ y2,
                                             const short* __restrict__ gf,
                                             float* __restrict__ out) {
    __shared__ short bbuf[3][66 * 16 * 8];   // 3-rotation row buffers; w66 0/65 = zero halo
    int h = blockIdx.x * 2, b = blockIdx.y;
    int tid = threadIdx.x;
    int wv = tid >> 6, l = tid & 63;
    int li = l & 15, lq = l >> 4;

    // zero halo rows (w66 = 0, 65) in all 3 buffers, once
    if (tid < 96) {
        int bi = tid >> 5, t2 = tid & 31;
        int row = (t2 >> 4) ? 65 : 0, g = t2 & 15;
        *(float4*)&bbuf[bi][(row * 16 + g) * 8] = (float4){0.f, 0.f, 0.f, 0.f};
    }

    f4v acc[2][4][4];
#pragma unroll
    for (int hs = 0; hs < 2; ++hs)
#pragma unroll
        for (int m = 0; m < 4; ++m)
#pragma unroll
            for (int n = 0; n < 4; ++n)
                acc[hs][m][n] = (f4v){0.f, 0.f, 0.f, 0.f};

    const h8v* GA = (const h8v*)gf;

    for (int half = 0; half < 2; ++half) {
        float4 sr[4];
        // prologue: stage rows h-1, h (latency exposed here only)
        stage_load(y2, sr, b, h - 1, half, tid);
        stage_write(bbuf[(h + 2) % 3], sr, tid);
        stage_load(y2, sr, b, h, half, tid);
        stage_write(bbuf[h % 3], sr, tid);
        __syncthreads();

        for (int ky = 0; ky < 3; ++ky) {
            // issue next row's loads FIRST; the MFMA phase hides their latency
            if (ky < 2)
                stage_load(y2, sr, b, h + ky + 1, half, tid);

            const h8v* B0 = (const h8v*)bbuf[(h + ky + 2) % 3];  // row h-1+ky
            const h8v* B1 = (const h8v*)bbuf[(h + ky) % 3];      // row h+ky

            for (int kx = 0; kx < 3; ++kx) {
                int kxy = ky * 3 + kx;
#pragma unroll
                for (int cc = 0; cc < 4; ++cc) {
                    int ccg = half * 4 + cc;
                    h8v Ah[4];
#pragma unroll
                    for (int m = 0; m < 4; ++m) {
                        size_t ab = ((((size_t)(kxy * 4 + wv) * 4 + m) * 8 + ccg)) * 64 + l;
                        Ah[m] = GA[ab];
                    }
#pragma unroll
                    for (int hs = 0; hs < 2; ++hs) {
                        const h8v* BH = hs ? B1 : B0;
                        h8v Bh[4];
#pragma unroll
                        for (int nt = 0; nt < 4; ++nt) {
                            int w66 = nt * 16 + li + kx;
                            int g = (cc * 4 + lq) ^ (w66 & 7);
                            Bh[nt] = BH[w66 * 16 + g];
                        }
#pragma unroll
                        for (int m = 0; m < 4; ++m)
#pragma unroll
                            for (int nt = 0; nt < 4; ++nt)
                                acc[hs][m][nt] = __builtin_amdgcn_mfma_f32_16x16x32_f16(Ah[m], Bh[nt], acc[hs][m][nt], 0, 0, 0);
                    }
                }
            }

            // write the prefetched row into the buffer nobody reads this phase
            // (distinct mod-3 from both read buffers -> no intra-phase race)
            if (ky < 2)
                stage_write(bbuf[(h + ky + 1) % 3], sr, tid);
            __syncthreads();
        }
    }

    // epilogue: out = y / (GSCALE * under_scaled), write NCHW for rows h and h+1
#pragma unroll
    for (int hs = 0; hs < 2; ++hs) {
        const short* nrow = y2 + (size_t)((b * 64 + h + hs) * 64) * 256;
#pragma unroll
        for (int m = 0; m < 4; ++m) {
            int co = wv * 64 + m * 16 + lq * 4;
#pragma unroll
            for (int nt = 0; nt < 4; ++nt) {
                int w = nt * 16 + li;
                ushort4 nh = *(const ushort4*)(nrow + (size_t)w * 256 + co);
                size_t ob = ((size_t)(b * 256 + co) * 64 + (h + hs)) * 64 + w;
                out[ob]            = h2f((short)nh.x) / (GSCALE * acc[hs][m][nt][0]);
                out[ob + 4096]     = h2f((short)nh.y) / (GSCALE * acc[hs][m][nt][1]);
                out[ob + 2 * 4096] = h2f((short)nh.z) / (GSCALE * acc[hs][m][nt][2]);
                out[ob + 3 * 4096] = h2f((short)nh.w) / (GSCALE * acc[hs][m][nt][3]);
            }
        }
    }
}

extern "C" void kernel_launch(void* const* d_in, const int* in_sizes, int n_in,
                              void* d_out, int out_size, void* d_ws, size_t ws_size,
                              hipStream_t stream) {
    const float* x   = (const float*)d_in[0];
    const float* wq0 = (const float*)d_in[1];
    const float* wq1 = (const float*)d_in[2];
    const float* g   = (const float*)d_in[3];
    float* out = (float*)d_out;
    short* y2 = (short*)d_ws;                        // 64MB fp16 plane
    short* gf = y2 + 33554432;                       // 1.18MB fp16
    float* wt0 = (float*)(gf + 589824);              // [25][256] f32
    float* wt1 = wt0 + 6400;

    prep_g<<<2304, 256, 0, stream>>>(g, wq0, wq1, gf, wt0, wt1);
    gabor<<<dim3(64, 32), 256, 0, stream>>>(x, wt0, wt1, y2);
    dn<<<dim3(32, 32), 256, 0, stream>>>(y2, gf, out);
}